// Round 14
// baseline (746.495 us; speedup 1.0000x reference)
//
#include <hip/hip_runtime.h>
#include <cstdint>
#include <cstddef>

#define NTOK 2048
#define DMODEL 1024
#define HD 64
#define MROWS 8192

using f16x8  = __attribute__((ext_vector_type(8))) _Float16;
using f16x4  = __attribute__((ext_vector_type(4))) _Float16;
using f32x4  = __attribute__((ext_vector_type(4))) float;
using f32x16 = __attribute__((ext_vector_type(16))) float;
using u16x8  = __attribute__((ext_vector_type(8))) unsigned short;
using u32x4  = __attribute__((ext_vector_type(4))) unsigned int;

#define Z16 {0.f,0.f,0.f,0.f,0.f,0.f,0.f,0.f,0.f,0.f,0.f,0.f,0.f,0.f,0.f,0.f}

__device__ __forceinline__ unsigned pkf16(float a, float b) {
  return __builtin_bit_cast(unsigned, __builtin_amdgcn_cvt_pkrtz(a, b));
}
__device__ __forceinline__ void plswap(unsigned &a, unsigned &b) {
  auto r = __builtin_amdgcn_permlane32_swap(a, b, false, false);
  a = r[0]; b = r[1];
}
// raw v_exp_f32: args always <= 0; flush-to-zero below -126 is correct for
// softmax tails.
__device__ __forceinline__ float fexp2(float x) {
  return __builtin_amdgcn_exp2f(x);
}
// nested fmaxf triple -> v_max3_f32
__device__ __forceinline__ float fmax3(float a, float b, float c) {
  return fmaxf(fmaxf(a, b), c);
}

// ---------------------------------------------------------------------------
// f32 -> f16 convert (x)
// ---------------------------------------------------------------------------
__global__ __launch_bounds__(256) void cvt_f32_f16(const float* __restrict__ in,
                                                   _Float16* __restrict__ out,
                                                   int n4, float scale) {
  int idx = blockIdx.x * 256 + threadIdx.x;
  if (idx < n4) {
    float4 v = reinterpret_cast<const float4*>(in)[idx];
    f16x4 o;
    o.x = (_Float16)(v.x * scale); o.y = (_Float16)(v.y * scale);
    o.z = (_Float16)(v.z * scale); o.w = (_Float16)(v.w * scale);
    reinterpret_cast<f16x4*>(out)[idx] = o;
  }
}

// both weight matrices in one launch; log2(e) folded into Wq
__global__ __launch_bounds__(256) void cvt_w(const float* __restrict__ Wk,
                                             const float* __restrict__ Wq,
                                             _Float16* __restrict__ Wkb,
                                             _Float16* __restrict__ Wqb) {
  const int idx = blockIdx.x * 256 + threadIdx.x;
  const float* in = blockIdx.y ? Wq : Wk;
  _Float16* out = blockIdx.y ? Wqb : Wkb;
  const float scale = blockIdx.y ? 1.4426950408889634f : 1.0f;
  float4 v = reinterpret_cast<const float4*>(in)[idx];
  f16x4 o;
  o.x = (_Float16)(v.x * scale); o.y = (_Float16)(v.y * scale);
  o.z = (_Float16)(v.z * scale); o.w = (_Float16)(v.w * scale);
  reinterpret_cast<f16x4*>(out)[idx] = o;
}

// ---------------------------------------------------------------------------
// f16 MFMA GEMM: Y[m][o] = sum_k X[m][k] * W[o][k]  (NT), Y stored f16.
// ---------------------------------------------------------------------------
#define GLDS16(g, l) __builtin_amdgcn_global_load_lds(                      \
    (const __attribute__((address_space(1))) void*)(g),                     \
    (__attribute__((address_space(3))) void*)(l), 16, 0, 0)

__global__ __launch_bounds__(256) void gemm_f16(
    const _Float16* __restrict__ X,
    const _Float16* __restrict__ Wk,
    const _Float16* __restrict__ Wq,
    _Float16* __restrict__ Kb,
    _Float16* __restrict__ Qb) {
  const _Float16* __restrict__ W = blockIdx.z ? Wq : Wk;
  _Float16* __restrict__ Y = blockIdx.z ? Qb : Kb;

  __shared__ _Float16 As[2][128 * 32];
  __shared__ _Float16 Bs[2][128 * 32];

  const int tid = threadIdx.x;
  const int lane = tid & 63;
  const int w = tid >> 6;
  const int m0 = blockIdx.x * 128;
  const int o0 = blockIdx.y * 128;

  const int srow = w * 32 + (lane >> 2);
  const int scol = (lane & 3) * 8;
  const _Float16* xsrc = X + (size_t)(m0 + srow) * DMODEL + scol;
  const _Float16* wsrc = W + (size_t)(o0 + srow) * DMODEL + scol;

  const int wr = w >> 1, wc = w & 1;
  const int arow = lane & 15, kg = lane >> 4;

  f32x4 zero = {0.f, 0.f, 0.f, 0.f};
  f32x4 acc[4][4];
#pragma unroll
  for (int mi = 0; mi < 4; ++mi)
#pragma unroll
    for (int ni = 0; ni < 4; ++ni) acc[mi][ni] = zero;

  GLDS16(xsrc,               &As[0][(w * 32) * 32]);
  GLDS16(xsrc + 16 * DMODEL, &As[0][(w * 32 + 16) * 32]);
  GLDS16(wsrc,               &Bs[0][(w * 32) * 32]);
  GLDS16(wsrc + 16 * DMODEL, &Bs[0][(w * 32 + 16) * 32]);

  for (int kt = 0; kt < 32; ++kt) {
    __syncthreads();
    if (kt + 1 < 32) {
      const int ko = (kt + 1) * 32;
      const int bn = (kt + 1) & 1;
      GLDS16(xsrc + ko,               &As[bn][(w * 32) * 32]);
      GLDS16(xsrc + ko + 16 * DMODEL, &As[bn][(w * 32 + 16) * 32]);
      GLDS16(wsrc + ko,               &Bs[bn][(w * 32) * 32]);
      GLDS16(wsrc + ko + 16 * DMODEL, &Bs[bn][(w * 32 + 16) * 32]);
    }
    const int buf = kt & 1;
    f16x8 af[4], bfr[4];
#pragma unroll
    for (int mi = 0; mi < 4; ++mi)
      af[mi] = *reinterpret_cast<const f16x8*>(
          &As[buf][(wr * 64 + mi * 16 + arow) * 32 + kg * 8]);
#pragma unroll
    for (int ni = 0; ni < 4; ++ni)
      bfr[ni] = *reinterpret_cast<const f16x8*>(
          &Bs[buf][(wc * 64 + ni * 16 + arow) * 32 + kg * 8]);
#pragma unroll
    for (int mi = 0; mi < 4; ++mi)
#pragma unroll
      for (int ni = 0; ni < 4; ++ni)
        acc[mi][ni] = __builtin_amdgcn_mfma_f32_16x16x32_f16(
            af[mi], bfr[ni], acc[mi][ni], 0, 0, 0);
  }

#pragma unroll
  for (int mi = 0; mi < 4; ++mi) {
#pragma unroll
    for (int ni = 0; ni < 4; ++ni) {
#pragma unroll
      for (int r = 0; r < 4; ++r) {
        const int m = m0 + wr * 64 + mi * 16 + kg * 4 + r;
        const int o = o0 + wc * 64 + ni * 16 + arow;
        Y[(size_t)m * DMODEL + o] = (_Float16)acc[mi][ni][r];
      }
    }
  }
}

// ---------------------------------------------------------------------------
// Combined pack kernel (grid.y: 0 = pack Q rows, 1 = pack K transposed).
// y=0: Qp[bh][rt(32-row tiles)][ks][lane][8]  = Q_head[rt*32+(l&31)][ks*16+(l>>5)*8+e]
// y=1: KTp[bh][jt][ds][ks][lane][8] = K_head[jt*64+ks*16+(l>>5)*8+e][ds*32+(l&31)]
// ---------------------------------------------------------------------------
__global__ __launch_bounds__(256) void pack_qkt(
    const _Float16* __restrict__ Qb,
    const _Float16* __restrict__ Kb,
    _Float16* __restrict__ Qp,
    _Float16* __restrict__ KTp) {
  const int blk = blockIdx.x;
  const int bh = blk >> 5;
  const int t64 = blk & 31;
  const int b = bh >> 4, h = bh & 15;
  const int tid = threadIdx.x;
  const _Float16* Src = blockIdx.y ? Kb : Qb;

  __shared__ _Float16 t[64][72];
#pragma unroll
  for (int rr = 0; rr < 2; ++rr) {
    const int c = tid + rr * 256;
    const int jr = c >> 3, dcol = (c & 7) * 8;
    *reinterpret_cast<f16x8*>(&t[jr][dcol]) =
        *reinterpret_cast<const f16x8*>(
            &Src[(size_t)(b * NTOK + t64 * 64 + jr) * DMODEL + h * HD + dcol]);
  }
  __syncthreads();
  if (blockIdx.y == 0) {
#pragma unroll
    for (int rr = 0; rr < 2; ++rr) {
      const int cI = tid + rr * 256;   // (rs,ks,l)
      const int rs = cI >> 8, ks = (cI >> 6) & 3, l = cI & 63;
      f16x8 v = *reinterpret_cast<const f16x8*>(
          &t[rs * 32 + (l & 31)][ks * 16 + (l >> 5) * 8]);
      const size_t ch = ((size_t)(bh * 64 + t64 * 2 + rs) * 4 + ks) * 512 + l * 8;
      *reinterpret_cast<f16x8*>(&Qp[ch]) = v;
    }
  } else {
#pragma unroll
    for (int rr = 0; rr < 2; ++rr) {
      const int cI = tid + rr * 256;   // (ds,ks,l)
      const int ds = cI >> 8, ks = (cI >> 6) & 3, l = cI & 63;
      const int col = ds * 32 + (l & 31);
      const int row0 = ks * 16 + (l >> 5) * 8;
      f16x8 v;
#pragma unroll
      for (int e = 0; e < 8; ++e) v[e] = t[row0 + e][col];
      const size_t ch = (((size_t)(bh * 32 + t64) * 2 + ds) * 4 + ks) * 512 + l * 8;
      *reinterpret_cast<f16x8*>(&KTp[ch]) = v;
    }
  }
}

// ---------------------------------------------------------------------------
// Swapped-operand MFMA flash attention, SPLIT-J (flash merge).
// r13 lesson: occupancy was REGISTER-capped at the launch_bounds(256,3)
// floor (allocator used the full ~680-reg budget), not grid-capped; pipes
// ran nearly additive (MFMA 32us + VALU 67us ~= 112us total).
// Fix: __launch_bounds__(256,6) caps allocation at ~340 regs (true live set
// ~130) -> up to 6 waves/SIMD resident -> cross-pipe overlap (m114).
// Also: row-max tree via v_max3 (16 values: 7 ops vs 15).
// Inner loop otherwise identical to r12/r13 (j-tile=32, in-place exp2,
// defer-max THR=8 with LDS-routed per-row rescale, cvt_pkrtz+permlane32_swap
// repack); end flash-merge of the two j-halves via LDS.
// ---------------------------------------------------------------------------
__global__ __launch_bounds__(256, 6) void attn_mfma(
    const _Float16* __restrict__ Kb,
    const _Float16* __restrict__ Qp,
    const _Float16* __restrict__ KTp,
    float* __restrict__ out) {
  const int bid = blockIdx.x;
  const int myid = (bid & 7) * 256 + (bid >> 3);   // 2048 blocks, bijective
  const int bh = myid >> 5;                        // 32 blocks per head
  const int itile = myid & 31;
  const int b = bh >> 4, h = bh & 15;
  const int tid = threadIdx.x, lane = tid & 63, w = tid >> 6;
  const int l31 = lane & 31;
  const int hi = lane >> 5;
  const int hi8 = hi * 8;
  const int i_sub = w & 1;                         // which 32-row i-block
  const int jh = w >> 1;                           // which j-half
  const int i0 = itile * 64 + i_sub * 32;

  const _Float16* Kh   = Kb + (size_t)b * NTOK * DMODEL + h * HD;
  const _Float16* qpp  = Qp  + (size_t)bh * 131072 + lane * 8;
  const _Float16* ktpp = KTp + (size_t)bh * 131072 + lane * 8;

  __shared__ float scl[4][32];       // per-wave rescale routing line
  __shared__ float mM[2][2][32];     // [i_sub][jh][row] running max
  __shared__ float lsM[2][2][32];    // [i_sub][jh][row] row sum
  __shared__ float obuf[2][32][64];  // wave-B scaled O: [i_sub][reg][lane]

  // B-frags of K_i for QK^T (one-time, uncoalesced but tiny)
  f16x8 kbf[4];
#pragma unroll
  for (int ks = 0; ks < 4; ++ks)
    kbf[ks] = *reinterpret_cast<const f16x8*>(
        &Kh[(size_t)(i0 + l31) * DMODEL + ks * 16 + hi8]);

  const f32x16 z16v = Z16;
  f32x16 o0 = z16v, o1 = z16v;
  float mreg = -1e30f, ls = 0.f;

  const int jt0 = jh * 32;
  for (int jt = jt0; jt < jt0 + 32; ++jt) {
    // ---- Q fragments for this 32-j tile ----
    f16x8 q[4];
#pragma unroll
    for (int ks = 0; ks < 4; ++ks)
      q[ks] = *reinterpret_cast<const f16x8*>(qpp + ((size_t)jt * 4 + ks) * 512);

    // ---- QK^T: S^T(32j x 32i), lane holds col i=l31, 16 j's in regs ----
    f32x16 s = z16v;
    __builtin_amdgcn_s_setprio(1);
#pragma unroll
    for (int ks = 0; ks < 4; ++ks)
      s = __builtin_amdgcn_mfma_f32_32x32x16_f16(q[ks], kbf[ks], s, 0, 0, 0);
    __builtin_amdgcn_s_setprio(0);

    // ---- KT fragments (independent of softmax; latency hidden under it) ----
    f16x8 kt0[2], kt1[2];
    {
      const size_t base = ((size_t)(jt >> 1) * 8 + (size_t)(jt & 1) * 2) * 512;
#pragma unroll
      for (int kk = 0; kk < 2; ++kk) {
        kt0[kk] = *reinterpret_cast<const f16x8*>(ktpp + base + (size_t)kk * 512);
        kt1[kk] = *reinterpret_cast<const f16x8*>(ktpp + base + (size_t)(4 + kk) * 512);
      }
    }

    // ---- row max via v_max3 (16 values: 5+2 max3 + 1 max) ----
    float t0 = fmax3(s[0], s[1], s[2]);
    float t1 = fmax3(s[3], s[4], s[5]);
    float t2 = fmax3(s[6], s[7], s[8]);
    float t3 = fmax3(s[9], s[10], s[11]);
    float t4 = fmax3(s[12], s[13], s[14]);
    float pm = fmaxf(fmax3(t0, t1, t2), fmax3(t3, t4, s[15]));
    pm = fmaxf(pm, __shfl_xor(pm, 32));

    // ---- defer-max rescale (rare; per-row factor routed via LDS line) ----
    if (!__all(pm <= mreg + 8.0f)) {
      const float mn = fmaxf(mreg, pm);
      const float sc = fexp2(mreg - mn);
      ls *= sc;
      mreg = mn;
      scl[w][l31] = sc;
#pragma unroll
      for (int r = 0; r < 16; ++r) {
        const int il = (r & 3) + 8 * (r >> 2) + 4 * hi;
        const float scr = scl[w][il];
        o0[r] *= scr; o1[r] *= scr;
      }
    }

    // ---- exp2 in place (scores pre-scaled by log2 e) ----
#pragma unroll
    for (int r = 0; r < 16; ++r) s[r] = fexp2(s[r] - mreg);
    {
      float l0 = (s[0] + s[4]) + (s[8] + s[12]);
      float l1 = (s[1] + s[5]) + (s[9] + s[13]);
      float l2 = (s[2] + s[6]) + (s[10] + s[14]);
      float l3 = (s[3] + s[7]) + (s[11] + s[15]);
      ls += (l0 + l1) + (l2 + l3);
    }

    // ---- in-register P repack (r4 chain, proven by r4==r5) ----
    f16x8 pfr[2];
    {
      unsigned a0 = pkf16(s[0], s[1]),  b0 = pkf16(s[4], s[5]);
      unsigned a1 = pkf16(s[2], s[3]),  b1 = pkf16(s[6], s[7]);
      plswap(a0, b0); plswap(a1, b1);
      u32x4 t; t[0] = a0; t[1] = a1; t[2] = b0; t[3] = b1;
      pfr[0] = __builtin_bit_cast(f16x8, t);
      unsigned a2 = pkf16(s[8], s[9]),   b2 = pkf16(s[12], s[13]);
      unsigned a3 = pkf16(s[10], s[11]), b3 = pkf16(s[14], s[15]);
      plswap(a2, b2); plswap(a3, b3);
      t[0] = a2; t[1] = a3; t[2] = b2; t[3] = b3;
      pfr[1] = __builtin_bit_cast(f16x8, t);
    }

    // ---- PV ----
    __builtin_amdgcn_s_setprio(1);
#pragma unroll
    for (int kk = 0; kk < 2; ++kk) {
      o0 = __builtin_amdgcn_mfma_f32_32x32x16_f16(pfr[kk], kt0[kk], o0, 0, 0, 0);
      o1 = __builtin_amdgcn_mfma_f32_32x32x16_f16(pfr[kk], kt1[kk], o1, 0, 0, 0);
    }
    __builtin_amdgcn_s_setprio(0);
  }

  // ---- flash merge of the two j-halves ----
  mM[i_sub][jh][l31]  = mreg;                       // both hi halves: same value
  lsM[i_sub][jh][l31] = ls + __shfl_xor(ls, 32);
  __syncthreads();

  if (jh == 1) {
    // wave B: scale own O to the combined max, park in LDS
#pragma unroll
    for (int r = 0; r < 16; ++r) {
      const int il = (r & 3) + 8 * (r >> 2) + 4 * hi;
      const float mS = fmaxf(mM[i_sub][0][il], mM[i_sub][1][il]);
      const float f = fexp2(mM[i_sub][1][il] - mS);
      obuf[i_sub][r][lane]      = o0[r] * f;
      obuf[i_sub][r + 16][lane] = o1[r] * f;
    }
  }
  __syncthreads();
  if (jh == 0) {
    // wave A: combine, normalize, store
#pragma unroll
    for (int r = 0; r < 16; ++r) {
      const int il = (r & 3) + 8 * (r >> 2) + 4 * hi;
      const float mA = mM[i_sub][0][il], mB = mM[i_sub][1][il];
      const float mS = fmaxf(mA, mB);
      const float fA = fexp2(mA - mS);
      const float fB = fexp2(mB - mS);
      const float lsS = lsM[i_sub][0][il] * fA + lsM[i_sub][1][il] * fB;
      const float inv = 1.0f / lsS;
      const size_t rowb = ((size_t)bh * NTOK + i0 + il) * HD;
      out[rowb + l31]      = (o0[r] * fA + obuf[i_sub][r][lane]) * inv;
      out[rowb + 32 + l31] = (o1[r] * fA + obuf[i_sub][r + 16][lane]) * inv;
    }
  }
}

extern "C" void kernel_launch(void* const* d_in, const int* in_sizes, int n_in,
                              void* d_out, int out_size, void* d_ws, size_t ws_size,
                              hipStream_t stream) {
  const float* x  = (const float*)d_in[0];
  const float* Wk = (const float*)d_in[1];
  const float* Wq = (const float*)d_in[2];
  // d_in[3] (Wv) is dead code in the reference — never read.
  float* out = (float*)d_out;

  // ws (f16 elems): [xb|Qp: 8388608][Wkb: 1048576][Wqb: 1048576]
  //                 [Kb: 8388608][Qb|KTp: 8388608]
  _Float16* xb  = (_Float16*)d_ws;
  _Float16* Qp  = xb;
  _Float16* Wkb = xb + (size_t)8388608;
  _Float16* Wqb = Wkb + (size_t)1048576;
  _Float16* Kb  = Wqb + (size_t)1048576;
  _Float16* Qb  = Kb + (size_t)8388608;
  _Float16* KTp = Qb;

  cvt_f32_f16<<<8192, 256, 0, stream>>>(x, xb, 2097152, 1.0f);
  cvt_w<<<dim3(1024, 2), 256, 0, stream>>>(Wk, Wq, Wkb, Wqb);

  dim3 ggrid(MROWS / 128, DMODEL / 128, 2);
  gemm_f16<<<ggrid, 256, 0, stream>>>(xb, Wkb, Wqb, Kb, Qb);

  pack_qkt<<<dim3(2048, 2), 256, 0, stream>>>(Qb, Kb, Qp, KTp);

  attn_mfma<<<2048, 256, 0, stream>>>(Kb, Qp, KTp, out);
}

// Round 15
// 177.656 us; speedup vs baseline: 4.2019x; 4.2019x over previous
//
#include <hip/hip_runtime.h>
#include <cstdint>
#include <cstddef>

#define NTOK 2048
#define DMODEL 1024
#define HD 64
#define MROWS 8192

using f16x8  = __attribute__((ext_vector_type(8))) _Float16;
using f16x4  = __attribute__((ext_vector_type(4))) _Float16;
using f32x4  = __attribute__((ext_vector_type(4))) float;
using f32x16 = __attribute__((ext_vector_type(16))) float;
using u32x4  = __attribute__((ext_vector_type(4))) unsigned int;

#define Z16 {0.f,0.f,0.f,0.f,0.f,0.f,0.f,0.f,0.f,0.f,0.f,0.f,0.f,0.f,0.f,0.f}

__device__ __forceinline__ unsigned pkf16(float a, float b) {
  return __builtin_bit_cast(unsigned, __builtin_amdgcn_cvt_pkrtz(a, b));
}
__device__ __forceinline__ void plswap(unsigned &a, unsigned &b) {
  auto r = __builtin_amdgcn_permlane32_swap(a, b, false, false);
  a = r[0]; b = r[1];
}
__device__ __forceinline__ float fexp2(float x) {
  return __builtin_amdgcn_exp2f(x);
}
__device__ __forceinline__ float fmax3(float a, float b, float c) {
  return fmaxf(fmaxf(a, b), c);
}

// ---------------------------------------------------------------------------
// f32 -> f16 convert (x)
// ---------------------------------------------------------------------------
__global__ __launch_bounds__(256) void cvt_f32_f16(const float* __restrict__ in,
                                                   _Float16* __restrict__ out,
                                                   int n4, float scale) {
  int idx = blockIdx.x * 256 + threadIdx.x;
  if (idx < n4) {
    float4 v = reinterpret_cast<const float4*>(in)[idx];
    f16x4 o;
    o.x = (_Float16)(v.x * scale); o.y = (_Float16)(v.y * scale);
    o.z = (_Float16)(v.z * scale); o.w = (_Float16)(v.w * scale);
    reinterpret_cast<f16x4*>(out)[idx] = o;
  }
}

// both weight matrices in one launch; log2(e) folded into Wq
__global__ __launch_bounds__(256) void cvt_w(const float* __restrict__ Wk,
                                             const float* __restrict__ Wq,
                                             _Float16* __restrict__ Wkb,
                                             _Float16* __restrict__ Wqb) {
  const int idx = blockIdx.x * 256 + threadIdx.x;
  const float* in = blockIdx.y ? Wq : Wk;
  _Float16* out = blockIdx.y ? Wqb : Wkb;
  const float scale = blockIdx.y ? 1.4426950408889634f : 1.0f;
  float4 v = reinterpret_cast<const float4*>(in)[idx];
  f16x4 o;
  o.x = (_Float16)(v.x * scale); o.y = (_Float16)(v.y * scale);
  o.z = (_Float16)(v.z * scale); o.w = (_Float16)(v.w * scale);
  reinterpret_cast<f16x4*>(out)[idx] = o;
}

// ---------------------------------------------------------------------------
// f16 MFMA GEMM with FUSED PACK epilogue.
// Computes Y = X @ W^T (128x128 tile) and writes it DIRECTLY in the packed
// fragment layout (no row-major intermediate):
//   z=1 (Q): Qp[bh][rt(64x32rows)][ks(4)][lane][8]
//            = Y_head[rt*32+(l&31)][ks*16+(l>>5)*8+e]
//   z=0 (K): Kp, same layout (serves attn's kbf B-frags directly).
// A 128x128 tile covers whole 512-f16 chunks: 2 heads x 4 rt x 4 ks.
// Epilogue: acc -> LDS tile T[128][136] (aliases staging arena, barriered),
// then 16B-coalesced chunk reads -> global stores.
// ---------------------------------------------------------------------------
#define GLDS16(g, l) __builtin_amdgcn_global_load_lds(                      \
    (const __attribute__((address_space(1))) void*)(g),                     \
    (__attribute__((address_space(3))) void*)(l), 16, 0, 0)

__global__ __launch_bounds__(256) void gemm_pack_f16(
    const _Float16* __restrict__ X,
    const _Float16* __restrict__ Wk,
    const _Float16* __restrict__ Wq,
    _Float16* __restrict__ Kp,
    _Float16* __restrict__ Qp) {
  const bool isQ = blockIdx.z != 0;
  const _Float16* __restrict__ W = isQ ? Wq : Wk;

  // arena: K-loop staging (As 2x4096 | Bs 2x4096 = 16384 f16) reused as the
  // epilogue tile T[128][136] = 17408 f16 (barrier-separated lifetimes).
  __shared__ _Float16 arena[17408];
  _Float16* As = arena;           // [2][4096]
  _Float16* Bs = arena + 8192;    // [2][4096]

  const int tid = threadIdx.x;
  const int lane = tid & 63;
  const int w = tid >> 6;
  const int m0 = blockIdx.x * 128;
  const int o0 = blockIdx.y * 128;

  const int srow = w * 32 + (lane >> 2);
  const int scol = (lane & 3) * 8;
  const _Float16* xsrc = X + (size_t)(m0 + srow) * DMODEL + scol;
  const _Float16* wsrc = W + (size_t)(o0 + srow) * DMODEL + scol;

  const int wr = w >> 1, wc = w & 1;
  const int arow = lane & 15, kg = lane >> 4;
  const int l31 = lane & 31, hi8 = (lane >> 5) * 8;

  f32x4 zero = {0.f, 0.f, 0.f, 0.f};
  f32x4 acc[4][4];
#pragma unroll
  for (int mi = 0; mi < 4; ++mi)
#pragma unroll
    for (int ni = 0; ni < 4; ++ni) acc[mi][ni] = zero;

  GLDS16(xsrc,               &As[(w * 32) * 32]);
  GLDS16(xsrc + 16 * DMODEL, &As[(w * 32 + 16) * 32]);
  GLDS16(wsrc,               &Bs[(w * 32) * 32]);
  GLDS16(wsrc + 16 * DMODEL, &Bs[(w * 32 + 16) * 32]);

  for (int kt = 0; kt < 32; ++kt) {
    __syncthreads();
    if (kt + 1 < 32) {
      const int ko = (kt + 1) * 32;
      const int bo = ((kt + 1) & 1) * 4096;
      GLDS16(xsrc + ko,               &As[bo + (w * 32) * 32]);
      GLDS16(xsrc + ko + 16 * DMODEL, &As[bo + (w * 32 + 16) * 32]);
      GLDS16(wsrc + ko,               &Bs[bo + (w * 32) * 32]);
      GLDS16(wsrc + ko + 16 * DMODEL, &Bs[bo + (w * 32 + 16) * 32]);
    }
    const int bo = (kt & 1) * 4096;
    f16x8 af[4], bfr[4];
#pragma unroll
    for (int mi = 0; mi < 4; ++mi)
      af[mi] = *reinterpret_cast<const f16x8*>(
          &As[bo + (wr * 64 + mi * 16 + arow) * 32 + kg * 8]);
#pragma unroll
    for (int ni = 0; ni < 4; ++ni)
      bfr[ni] = *reinterpret_cast<const f16x8*>(
          &Bs[bo + (wc * 64 + ni * 16 + arow) * 32 + kg * 8]);
#pragma unroll
    for (int mi = 0; mi < 4; ++mi)
#pragma unroll
      for (int ni = 0; ni < 4; ++ni)
        acc[mi][ni] = __builtin_amdgcn_mfma_f32_16x16x32_f16(
            af[mi], bfr[ni], acc[mi][ni], 0, 0, 0);
  }

  // ---- epilogue: acc -> T (f16), then packed chunk emission ----
  __syncthreads();                 // all waves done reading staging LDS
  _Float16* T = arena;             // [128][136]
#pragma unroll
  for (int mi = 0; mi < 4; ++mi)
#pragma unroll
    for (int ni = 0; ni < 4; ++ni)
#pragma unroll
      for (int r = 0; r < 4; ++r)
        T[(wr * 64 + mi * 16 + kg * 4 + r) * 136 + wc * 64 + ni * 16 + arow] =
            (_Float16)acc[mi][ni][r];
  __syncthreads();

  const int b = m0 >> 11;
  _Float16* RowDst = isQ ? Qp : Kp;
  // 32 row-chunks (2 heads x 4 rt x 4 ks); wave w emits 8
#pragma unroll
  for (int k = 0; k < 8; ++k) {
    const int c = w * 8 + k;
    const int hl = c >> 4, rtl = (c >> 2) & 3, ks = c & 3;
    f16x8 v = *reinterpret_cast<const f16x8*>(
        &T[(rtl * 32 + l31) * 136 + hl * 64 + ks * 16 + hi8]);
    const int bh = b * 16 + (o0 >> 6) + hl;
    const int rt = ((m0 & 2047) >> 5) + rtl;
    const size_t ch = ((size_t)(bh * 64 + rt) * 4 + ks) * 512 + (size_t)lane * 8;
    *reinterpret_cast<f16x8*>(&RowDst[ch]) = v;
  }
}

// ---------------------------------------------------------------------------
// pack_kt: builds KTp from packed-row Kp.
// KTp[bh][jt(32 x 64rows)][ds(2)][ks(4)][lane][8]
//   = K_head[jt*64 + ks*16 + (l>>5)*8 + e][ds*32 + (l&31)]
// Stage the 64x64 row-group from 8 Kp chunks (16B LDS writes), then
// column-gather the 8 KT chunks.
// ---------------------------------------------------------------------------
__global__ __launch_bounds__(256) void pack_kt(
    const _Float16* __restrict__ Kp,
    _Float16* __restrict__ KTp) {
  const int blk = blockIdx.x;
  const int bh = blk >> 5;
  const int t64 = blk & 31;          // = jt
  const int tid = threadIdx.x;
  const int l = tid & 63;

  __shared__ _Float16 t[64][72];
#pragma unroll
  for (int pass = 0; pass < 2; ++pass) {
    const int idx = pass * 4 + (tid >> 6);   // 8 source chunks: rs(2) x ks(4)
    const int rs = idx >> 2, ks = idx & 3;
    f16x8 v = *reinterpret_cast<const f16x8*>(
        &Kp[((size_t)(bh * 64 + t64 * 2 + rs) * 4 + ks) * 512 + (size_t)l * 8]);
    *reinterpret_cast<f16x8*>(&t[rs * 32 + (l & 31)][ks * 16 + (l >> 5) * 8]) = v;
  }
  __syncthreads();
#pragma unroll
  for (int pass = 0; pass < 2; ++pass) {
    const int idx = pass * 4 + (tid >> 6);   // 8 dest chunks: ds(2) x ks(4)
    const int ds = idx >> 2, ks = idx & 3;
    const int row0 = ks * 16 + (l >> 5) * 8;
    const int col = ds * 32 + (l & 31);
    f16x8 v;
#pragma unroll
    for (int e = 0; e < 8; ++e) v[e] = t[row0 + e][col];
    const size_t ch = (((size_t)(bh * 32 + t64) * 2 + ds) * 4 + ks) * 512 + (size_t)l * 8;
    *reinterpret_cast<f16x8*>(&KTp[ch]) = v;
  }
}

// ---------------------------------------------------------------------------
// Swapped-operand MFMA flash attention, SPLIT-J (flash merge) — r13 inner
// loop with launch_bounds back at (256,3): r14 proved the ~140-reg live set
// spills catastrophically when forced below it; 3 waves/SIMD is the clean cap.
// kbf now reads packed Kp (identical fragment layout, coalesced).
// ---------------------------------------------------------------------------
__global__ __launch_bounds__(256, 3) void attn_mfma(
    const _Float16* __restrict__ Kp,
    const _Float16* __restrict__ Qp,
    const _Float16* __restrict__ KTp,
    float* __restrict__ out) {
  const int bid = blockIdx.x;
  const int myid = (bid & 7) * 256 + (bid >> 3);   // 2048 blocks, bijective
  const int bh = myid >> 5;                        // 32 blocks per head
  const int itile = myid & 31;
  const int tid = threadIdx.x, lane = tid & 63, w = tid >> 6;
  const int l31 = lane & 31;
  const int hi = lane >> 5;
  const int i_sub = w & 1;                         // which 32-row i-block
  const int jh = w >> 1;                           // which j-half
  const int i0 = itile * 64 + i_sub * 32;

  const _Float16* kpp  = Kp  + (size_t)bh * 131072 + lane * 8;
  const _Float16* qpp  = Qp  + (size_t)bh * 131072 + lane * 8;
  const _Float16* ktpp = KTp + (size_t)bh * 131072 + lane * 8;

  __shared__ float scl[4][32];       // per-wave rescale routing line
  __shared__ float mM[2][2][32];     // [i_sub][jh][row] running max
  __shared__ float lsM[2][2][32];    // [i_sub][jh][row] row sum
  __shared__ float obuf[2][32][64];  // wave-B scaled O: [i_sub][reg][lane]

  // B-frags of K_i for QK^T from packed Kp (coalesced)
  f16x8 kbf[4];
#pragma unroll
  for (int ks = 0; ks < 4; ++ks)
    kbf[ks] = *reinterpret_cast<const f16x8*>(
        kpp + ((size_t)(i0 >> 5) * 4 + ks) * 512);

  const f32x16 z16v = Z16;
  f32x16 o0 = z16v, o1 = z16v;
  float mreg = -1e30f, ls = 0.f;

  const int jt0 = jh * 32;
  for (int jt = jt0; jt < jt0 + 32; ++jt) {
    f16x8 q[4];
#pragma unroll
    for (int ks = 0; ks < 4; ++ks)
      q[ks] = *reinterpret_cast<const f16x8*>(qpp + ((size_t)jt * 4 + ks) * 512);

    f32x16 s = z16v;
    __builtin_amdgcn_s_setprio(1);
#pragma unroll
    for (int ks = 0; ks < 4; ++ks)
      s = __builtin_amdgcn_mfma_f32_32x32x16_f16(q[ks], kbf[ks], s, 0, 0, 0);
    __builtin_amdgcn_s_setprio(0);

    f16x8 kt0[2], kt1[2];
    {
      const size_t base = ((size_t)(jt >> 1) * 8 + (size_t)(jt & 1) * 2) * 512;
#pragma unroll
      for (int kk = 0; kk < 2; ++kk) {
        kt0[kk] = *reinterpret_cast<const f16x8*>(ktpp + base + (size_t)kk * 512);
        kt1[kk] = *reinterpret_cast<const f16x8*>(ktpp + base + (size_t)(4 + kk) * 512);
      }
    }

    // row max via v_max3
    float t0 = fmax3(s[0], s[1], s[2]);
    float t1 = fmax3(s[3], s[4], s[5]);
    float t2 = fmax3(s[6], s[7], s[8]);
    float t3 = fmax3(s[9], s[10], s[11]);
    float t4 = fmax3(s[12], s[13], s[14]);
    float pm = fmaxf(fmax3(t0, t1, t2), fmax3(t3, t4, s[15]));
    pm = fmaxf(pm, __shfl_xor(pm, 32));

    if (!__all(pm <= mreg + 8.0f)) {
      const float mn = fmaxf(mreg, pm);
      const float sc = fexp2(mreg - mn);
      ls *= sc;
      mreg = mn;
      scl[w][l31] = sc;
#pragma unroll
      for (int r = 0; r < 16; ++r) {
        const int il = (r & 3) + 8 * (r >> 2) + 4 * hi;
        const float scr = scl[w][il];
        o0[r] *= scr; o1[r] *= scr;
      }
    }

#pragma unroll
    for (int r = 0; r < 16; ++r) s[r] = fexp2(s[r] - mreg);
    {
      float l0 = (s[0] + s[4]) + (s[8] + s[12]);
      float l1 = (s[1] + s[5]) + (s[9] + s[13]);
      float l2 = (s[2] + s[6]) + (s[10] + s[14]);
      float l3 = (s[3] + s[7]) + (s[11] + s[15]);
      ls += (l0 + l1) + (l2 + l3);
    }

    f16x8 pfr[2];
    {
      unsigned a0 = pkf16(s[0], s[1]),  b0 = pkf16(s[4], s[5]);
      unsigned a1 = pkf16(s[2], s[3]),  b1 = pkf16(s[6], s[7]);
      plswap(a0, b0); plswap(a1, b1);
      u32x4 t; t[0] = a0; t[1] = a1; t[2] = b0; t[3] = b1;
      pfr[0] = __builtin_bit_cast(f16x8, t);
      unsigned a2 = pkf16(s[8], s[9]),   b2 = pkf16(s[12], s[13]);
      unsigned a3 = pkf16(s[10], s[11]), b3 = pkf16(s[14], s[15]);
      plswap(a2, b2); plswap(a3, b3);
      t[0] = a2; t[1] = a3; t[2] = b2; t[3] = b3;
      pfr[1] = __builtin_bit_cast(f16x8, t);
    }

    __builtin_amdgcn_s_setprio(1);
#pragma unroll
    for (int kk = 0; kk < 2; ++kk) {
      o0 = __builtin_amdgcn_mfma_f32_32x32x16_f16(pfr[kk], kt0[kk], o0, 0, 0, 0);
      o1 = __builtin_amdgcn_mfma_f32_32x32x16_f16(pfr[kk], kt1[kk], o1, 0, 0, 0);
    }
    __builtin_amdgcn_s_setprio(0);
  }

  // ---- flash merge of the two j-halves ----
  mM[i_sub][jh][l31]  = mreg;
  lsM[i_sub][jh][l31] = ls + __shfl_xor(ls, 32);
  __syncthreads();

  if (jh == 1) {
#pragma unroll
    for (int r = 0; r < 16; ++r) {
      const int il = (r & 3) + 8 * (r >> 2) + 4 * hi;
      const float mS = fmaxf(mM[i_sub][0][il], mM[i_sub][1][il]);
      const float f = fexp2(mM[i_sub][1][il] - mS);
      obuf[i_sub][r][lane]      = o0[r] * f;
      obuf[i_sub][r + 16][lane] = o1[r] * f;
    }
  }
  __syncthreads();
  if (jh == 0) {
#pragma unroll
    for (int r = 0; r < 16; ++r) {
      const int il = (r & 3) + 8 * (r >> 2) + 4 * hi;
      const float mA = mM[i_sub][0][il], mB = mM[i_sub][1][il];
      const float mS = fmaxf(mA, mB);
      const float fA = fexp2(mA - mS);
      const float fB = fexp2(mB - mS);
      const float lsS = lsM[i_sub][0][il] * fA + lsM[i_sub][1][il] * fB;
      const float inv = 1.0f / lsS;
      const size_t rowb = ((size_t)bh * NTOK + i0 + il) * HD;
      out[rowb + l31]      = (o0[r] * fA + obuf[i_sub][r][lane]) * inv;
      out[rowb + 32 + l31] = (o1[r] * fA + obuf[i_sub][r + 16][lane]) * inv;
    }
  }
}

extern "C" void kernel_launch(void* const* d_in, const int* in_sizes, int n_in,
                              void* d_out, int out_size, void* d_ws, size_t ws_size,
                              hipStream_t stream) {
  const float* x  = (const float*)d_in[0];
  const float* Wk = (const float*)d_in[1];
  const float* Wq = (const float*)d_in[2];
  // d_in[3] (Wv) is dead code in the reference — never read.
  float* out = (float*)d_out;

  // ws (f16 elems): [xb|KTp: 8388608][Wkb: 1048576][Wqb: 1048576]
  //                 [Kp: 8388608][Qp: 8388608]  = 54.5 MB
  // xb dead after GEMM; pack_kt writes KTp into its space afterwards.
  _Float16* xb  = (_Float16*)d_ws;
  _Float16* KTp = xb;
  _Float16* Wkb = xb + (size_t)8388608;
  _Float16* Wqb = Wkb + (size_t)1048576;
  _Float16* Kp  = Wqb + (size_t)1048576;
  _Float16* Qp  = Kp + (size_t)8388608;

  cvt_f32_f16<<<8192, 256, 0, stream>>>(x, xb, 2097152, 1.0f);
  cvt_w<<<dim3(1024, 2), 256, 0, stream>>>(Wk, Wq, Wkb, Wqb);

  dim3 ggrid(MROWS / 128, DMODEL / 128, 2);   // z=0 -> Kp, z=1 -> Qp
  gemm_pack_f16<<<ggrid, 256, 0, stream>>>(xb, Wkb, Wqb, Kp, Qp);

  pack_kt<<<2048, 256, 0, stream>>>(Kp, KTp);

  attn_mfma<<<2048, 256, 0, stream>>>(Kp, Qp, KTp, out);
}

// Round 16
// 177.531 us; speedup vs baseline: 4.2049x; 1.0007x over previous
//
#include <hip/hip_runtime.h>
#include <cstdint>
#include <cstddef>

#define NTOK 2048
#define DMODEL 1024
#define HD 64
#define MROWS 8192

using f16x8  = __attribute__((ext_vector_type(8))) _Float16;
using f16x4  = __attribute__((ext_vector_type(4))) _Float16;
using f16x2  = __attribute__((ext_vector_type(2))) _Float16;
using f32x4  = __attribute__((ext_vector_type(4))) float;
using f32x16 = __attribute__((ext_vector_type(16))) float;
using u32x4  = __attribute__((ext_vector_type(4))) unsigned int;

#define Z16 {0.f,0.f,0.f,0.f,0.f,0.f,0.f,0.f,0.f,0.f,0.f,0.f,0.f,0.f,0.f,0.f}

extern "C" __device__ _Float16 __ocml_exp2_f16(_Float16);

__device__ __forceinline__ void plswap(unsigned &a, unsigned &b) {
  auto r = __builtin_amdgcn_permlane32_swap(a, b, false, false);
  a = r[0]; b = r[1];
}
__device__ __forceinline__ float fexp2(float x) {
  return __builtin_amdgcn_exp2f(x);
}
__device__ __forceinline__ float fmax3(float a, float b, float c) {
  return fmaxf(fmaxf(a, b), c);
}
// pack two f16 (lo, hi) into one u32 (v_pack_b32_f16)
__device__ __forceinline__ unsigned pk2h(_Float16 lo, _Float16 hi) {
  return (unsigned)__builtin_bit_cast(unsigned short, lo) |
         ((unsigned)__builtin_bit_cast(unsigned short, hi) << 16);
}

// ---------------------------------------------------------------------------
// f32 -> f16 convert (x)
// ---------------------------------------------------------------------------
__global__ __launch_bounds__(256) void cvt_f32_f16(const float* __restrict__ in,
                                                   _Float16* __restrict__ out,
                                                   int n4, float scale) {
  int idx = blockIdx.x * 256 + threadIdx.x;
  if (idx < n4) {
    float4 v = reinterpret_cast<const float4*>(in)[idx];
    f16x4 o;
    o.x = (_Float16)(v.x * scale); o.y = (_Float16)(v.y * scale);
    o.z = (_Float16)(v.z * scale); o.w = (_Float16)(v.w * scale);
    reinterpret_cast<f16x4*>(out)[idx] = o;
  }
}

// both weight matrices in one launch; log2(e) folded into Wq
__global__ __launch_bounds__(256) void cvt_w(const float* __restrict__ Wk,
                                             const float* __restrict__ Wq,
                                             _Float16* __restrict__ Wkb,
                                             _Float16* __restrict__ Wqb) {
  const int idx = blockIdx.x * 256 + threadIdx.x;
  const float* in = blockIdx.y ? Wq : Wk;
  _Float16* out = blockIdx.y ? Wqb : Wkb;
  const float scale = blockIdx.y ? 1.4426950408889634f : 1.0f;
  float4 v = reinterpret_cast<const float4*>(in)[idx];
  f16x4 o;
  o.x = (_Float16)(v.x * scale); o.y = (_Float16)(v.y * scale);
  o.z = (_Float16)(v.z * scale); o.w = (_Float16)(v.w * scale);
  reinterpret_cast<f16x4*>(out)[idx] = o;
}

// ---------------------------------------------------------------------------
// f16 MFMA GEMM with FUSED PACK epilogue (r15, unchanged).
// ---------------------------------------------------------------------------
#define GLDS16(g, l) __builtin_amdgcn_global_load_lds(                      \
    (const __attribute__((address_space(1))) void*)(g),                     \
    (__attribute__((address_space(3))) void*)(l), 16, 0, 0)

__global__ __launch_bounds__(256) void gemm_pack_f16(
    const _Float16* __restrict__ X,
    const _Float16* __restrict__ Wk,
    const _Float16* __restrict__ Wq,
    _Float16* __restrict__ Kp,
    _Float16* __restrict__ Qp) {
  const bool isQ = blockIdx.z != 0;
  const _Float16* __restrict__ W = isQ ? Wq : Wk;

  __shared__ _Float16 arena[17408];
  _Float16* As = arena;           // [2][4096]
  _Float16* Bs = arena + 8192;    // [2][4096]

  const int tid = threadIdx.x;
  const int lane = tid & 63;
  const int w = tid >> 6;
  const int m0 = blockIdx.x * 128;
  const int o0 = blockIdx.y * 128;

  const int srow = w * 32 + (lane >> 2);
  const int scol = (lane & 3) * 8;
  const _Float16* xsrc = X + (size_t)(m0 + srow) * DMODEL + scol;
  const _Float16* wsrc = W + (size_t)(o0 + srow) * DMODEL + scol;

  const int wr = w >> 1, wc = w & 1;
  const int arow = lane & 15, kg = lane >> 4;
  const int l31 = lane & 31, hi8 = (lane >> 5) * 8;

  f32x4 zero = {0.f, 0.f, 0.f, 0.f};
  f32x4 acc[4][4];
#pragma unroll
  for (int mi = 0; mi < 4; ++mi)
#pragma unroll
    for (int ni = 0; ni < 4; ++ni) acc[mi][ni] = zero;

  GLDS16(xsrc,               &As[(w * 32) * 32]);
  GLDS16(xsrc + 16 * DMODEL, &As[(w * 32 + 16) * 32]);
  GLDS16(wsrc,               &Bs[(w * 32) * 32]);
  GLDS16(wsrc + 16 * DMODEL, &Bs[(w * 32 + 16) * 32]);

  for (int kt = 0; kt < 32; ++kt) {
    __syncthreads();
    if (kt + 1 < 32) {
      const int ko = (kt + 1) * 32;
      const int bo = ((kt + 1) & 1) * 4096;
      GLDS16(xsrc + ko,               &As[bo + (w * 32) * 32]);
      GLDS16(xsrc + ko + 16 * DMODEL, &As[bo + (w * 32 + 16) * 32]);
      GLDS16(wsrc + ko,               &Bs[bo + (w * 32) * 32]);
      GLDS16(wsrc + ko + 16 * DMODEL, &Bs[bo + (w * 32 + 16) * 32]);
    }
    const int bo = (kt & 1) * 4096;
    f16x8 af[4], bfr[4];
#pragma unroll
    for (int mi = 0; mi < 4; ++mi)
      af[mi] = *reinterpret_cast<const f16x8*>(
          &As[bo + (wr * 64 + mi * 16 + arow) * 32 + kg * 8]);
#pragma unroll
    for (int ni = 0; ni < 4; ++ni)
      bfr[ni] = *reinterpret_cast<const f16x8*>(
          &Bs[bo + (wc * 64 + ni * 16 + arow) * 32 + kg * 8]);
#pragma unroll
    for (int mi = 0; mi < 4; ++mi)
#pragma unroll
      for (int ni = 0; ni < 4; ++ni)
        acc[mi][ni] = __builtin_amdgcn_mfma_f32_16x16x32_f16(
            af[mi], bfr[ni], acc[mi][ni], 0, 0, 0);
  }

  __syncthreads();
  _Float16* T = arena;             // [128][136]
#pragma unroll
  for (int mi = 0; mi < 4; ++mi)
#pragma unroll
    for (int ni = 0; ni < 4; ++ni)
#pragma unroll
      for (int r = 0; r < 4; ++r)
        T[(wr * 64 + mi * 16 + kg * 4 + r) * 136 + wc * 64 + ni * 16 + arow] =
            (_Float16)acc[mi][ni][r];
  __syncthreads();

  const int b = m0 >> 11;
  _Float16* RowDst = isQ ? Qp : Kp;
#pragma unroll
  for (int k = 0; k < 8; ++k) {
    const int c = w * 8 + k;
    const int hl = c >> 4, rtl = (c >> 2) & 3, ks = c & 3;
    f16x8 v = *reinterpret_cast<const f16x8*>(
        &T[(rtl * 32 + l31) * 136 + hl * 64 + ks * 16 + hi8]);
    const int bh = b * 16 + (o0 >> 6) + hl;
    const int rt = ((m0 & 2047) >> 5) + rtl;
    const size_t ch = ((size_t)(bh * 64 + rt) * 4 + ks) * 512 + (size_t)lane * 8;
    *reinterpret_cast<f16x8*>(&RowDst[ch]) = v;
  }
}

// ---------------------------------------------------------------------------
// pack_kt: builds KTp from packed-row Kp (r15, unchanged).
// ---------------------------------------------------------------------------
__global__ __launch_bounds__(256) void pack_kt(
    const _Float16* __restrict__ Kp,
    _Float16* __restrict__ KTp) {
  const int blk = blockIdx.x;
  const int bh = blk >> 5;
  const int t64 = blk & 31;
  const int tid = threadIdx.x;
  const int l = tid & 63;

  __shared__ _Float16 t[64][72];
#pragma unroll
  for (int pass = 0; pass < 2; ++pass) {
    const int idx = pass * 4 + (tid >> 6);
    const int rs = idx >> 2, ks = idx & 3;
    f16x8 v = *reinterpret_cast<const f16x8*>(
        &Kp[((size_t)(bh * 64 + t64 * 2 + rs) * 4 + ks) * 512 + (size_t)l * 8]);
    *reinterpret_cast<f16x8*>(&t[rs * 32 + (l & 31)][ks * 16 + (l >> 5) * 8]) = v;
  }
  __syncthreads();
#pragma unroll
  for (int pass = 0; pass < 2; ++pass) {
    const int idx = pass * 4 + (tid >> 6);
    const int ds = idx >> 2, ks = idx & 3;
    const int row0 = ks * 16 + (l >> 5) * 8;
    const int col = ds * 32 + (l & 31);
    f16x8 v;
#pragma unroll
    for (int e = 0; e < 8; ++e) v[e] = t[row0 + e][col];
    const size_t ch = (((size_t)(bh * 32 + t64) * 2 + ds) * 4 + ks) * 512 + (size_t)l * 8;
    *reinterpret_cast<f16x8*>(&KTp[ch]) = v;
  }
}

// ---------------------------------------------------------------------------
// Swapped-operand MFMA flash attention, SPLIT-J, VALU-dieted:
// r15 diagnosis: VALU busy ~65us is the binding resource; static count says
// the heavyweights are v_exp_f32 (16/tile, slow trans) and 64-bit indexed
// addressing. This round: (1) exp in f16 (d = s-m computed f32, |d|<=8 so
// f16 cvt err <= 2^-8 in the exponent; __ocml_exp2_f16 = v_exp_f16; P was
// f16 anyway), (2) ls via v_dot2_f32_f16 with ones (f32 accum), (3) all
// Q/KT loads via two bumped pointers with compile-time offsets, jt
// unrolled x2 (even/odd KT chunk patterns). Repack/plswap chain unchanged
// (r4-verified); defer-max + LDS-routed rescale unchanged.
// ---------------------------------------------------------------------------
__global__ __launch_bounds__(256, 3) void attn_mfma(
    const _Float16* __restrict__ Kp,
    const _Float16* __restrict__ Qp,
    const _Float16* __restrict__ KTp,
    float* __restrict__ out) {
  const int bid = blockIdx.x;
  const int myid = (bid & 7) * 256 + (bid >> 3);   // 2048 blocks, bijective
  const int bh = myid >> 5;                        // 32 blocks per head
  const int itile = myid & 31;
  const int tid = threadIdx.x, lane = tid & 63, w = tid >> 6;
  const int l31 = lane & 31;
  const int hi = lane >> 5;
  const int i_sub = w & 1;
  const int jh = w >> 1;
  const int i0 = itile * 64 + i_sub * 32;

  const _Float16* kpp  = Kp  + (size_t)bh * 131072 + lane * 8;
  const _Float16* qpp  = Qp  + (size_t)bh * 131072 + lane * 8;
  const _Float16* ktpp = KTp + (size_t)bh * 131072 + lane * 8;

  __shared__ float scl[4][32];
  __shared__ float mM[2][2][32];
  __shared__ float lsM[2][2][32];
  __shared__ float obuf[2][32][64];

  f16x8 kbf[4];
#pragma unroll
  for (int ks = 0; ks < 4; ++ks)
    kbf[ks] = *reinterpret_cast<const f16x8*>(
        kpp + ((size_t)(i0 >> 5) * 4 + ks) * 512);

  const f32x16 z16v = Z16;
  f32x16 o0 = z16v, o1 = z16v;
  float mreg = -1e30f, ls = 0.f;
  const f16x2 one2 = {(_Float16)1.f, (_Float16)1.f};

  // pointer-bumped bases for this j-half (even-jt pattern at +0, odd at fixed
  // immediate offsets; stride 4096 elems per jt-pair)
  const _Float16* qP  = qpp  + (size_t)jh * 65536;
  const _Float16* ktP = ktpp + (size_t)jh * 65536;

#define ATT_TILE(QO, KTO)                                                     \
  {                                                                           \
    f16x8 q[4];                                                               \
    _Pragma("unroll")                                                         \
    for (int ks = 0; ks < 4; ++ks)                                            \
      q[ks] = *reinterpret_cast<const f16x8*>(qP + (QO) + ks * 512);          \
    f32x16 s = z16v;                                                          \
    __builtin_amdgcn_s_setprio(1);                                            \
    _Pragma("unroll")                                                         \
    for (int ks = 0; ks < 4; ++ks)                                            \
      s = __builtin_amdgcn_mfma_f32_32x32x16_f16(q[ks], kbf[ks], s, 0, 0, 0); \
    __builtin_amdgcn_s_setprio(0);                                            \
    f16x8 kt0[2], kt1[2];                                                     \
    kt0[0] = *reinterpret_cast<const f16x8*>(ktP + (KTO));                    \
    kt0[1] = *reinterpret_cast<const f16x8*>(ktP + (KTO) + 512);              \
    kt1[0] = *reinterpret_cast<const f16x8*>(ktP + (KTO) + 2048);             \
    kt1[1] = *reinterpret_cast<const f16x8*>(ktP + (KTO) + 2560);             \
    float t0 = fmax3(s[0], s[1], s[2]);                                       \
    float t1 = fmax3(s[3], s[4], s[5]);                                       \
    float t2 = fmax3(s[6], s[7], s[8]);                                       \
    float t3 = fmax3(s[9], s[10], s[11]);                                     \
    float t4 = fmax3(s[12], s[13], s[14]);                                    \
    float pm = fmaxf(fmax3(t0, t1, t2), fmax3(t3, t4, s[15]));                \
    pm = fmaxf(pm, __shfl_xor(pm, 32));                                       \
    if (!__all(pm <= mreg + 8.0f)) {                                          \
      const float mn = fmaxf(mreg, pm);                                       \
      const float sc = fexp2(mreg - mn);                                      \
      ls *= sc;                                                               \
      mreg = mn;                                                              \
      scl[w][l31] = sc;                                                       \
      _Pragma("unroll")                                                       \
      for (int r = 0; r < 16; ++r) {                                          \
        const int il = (r & 3) + 8 * (r >> 2) + 4 * hi;                       \
        const float scr = scl[w][il];                                         \
        o0[r] *= scr; o1[r] *= scr;                                           \
      }                                                                       \
    }                                                                         \
    /* d = s - m in f32, exp in f16 (|d|<=8: cvt err <= 2^-8 of exponent) */  \
    _Float16 pe[16];                                                          \
    _Pragma("unroll")                                                         \
    for (int r = 0; r < 16; ++r)                                              \
      pe[r] = __ocml_exp2_f16((_Float16)(s[r] - mreg));                       \
    unsigned a0 = pk2h(pe[0], pe[1]),   b0 = pk2h(pe[4], pe[5]);              \
    unsigned a1 = pk2h(pe[2], pe[3]),   b1 = pk2h(pe[6], pe[7]);              \
    unsigned a2 = pk2h(pe[8], pe[9]),   b2 = pk2h(pe[12], pe[13]);            \
    unsigned a3 = pk2h(pe[10], pe[11]), b3 = pk2h(pe[14], pe[15]);            \
    /* ls += sum of this lane's 16 P values via fdot2 (f32 accum) */          \
    {                                                                         \
      float sA = __builtin_amdgcn_fdot2(__builtin_bit_cast(f16x2, a0), one2,  \
                                        0.f, false);                          \
      sA = __builtin_amdgcn_fdot2(__builtin_bit_cast(f16x2, a1), one2, sA, false);\
      sA = __builtin_amdgcn_fdot2(__builtin_bit_cast(f16x2, a2), one2, sA, false);\
      sA = __builtin_amdgcn_fdot2(__builtin_bit_cast(f16x2, a3), one2, sA, false);\
      float sB = __builtin_amdgcn_fdot2(__builtin_bit_cast(f16x2, b0), one2,  \
                                        0.f, false);                          \
      sB = __builtin_amdgcn_fdot2(__builtin_bit_cast(f16x2, b1), one2, sB, false);\
      sB = __builtin_amdgcn_fdot2(__builtin_bit_cast(f16x2, b2), one2, sB, false);\
      sB = __builtin_amdgcn_fdot2(__builtin_bit_cast(f16x2, b3), one2, sB, false);\
      ls += sA + sB;                                                          \
    }                                                                         \
    f16x8 pfr[2];                                                             \
    {                                                                         \
      plswap(a0, b0); plswap(a1, b1);                                         \
      u32x4 t; t[0] = a0; t[1] = a1; t[2] = b0; t[3] = b1;                    \
      pfr[0] = __builtin_bit_cast(f16x8, t);                                  \
      plswap(a2, b2); plswap(a3, b3);                                         \
      t[0] = a2; t[1] = a3; t[2] = b2; t[3] = b3;                             \
      pfr[1] = __builtin_bit_cast(f16x8, t);                                  \
    }                                                                         \
    __builtin_amdgcn_s_setprio(1);                                            \
    _Pragma("unroll")                                                         \
    for (int kk = 0; kk < 2; ++kk) {                                          \
      o0 = __builtin_amdgcn_mfma_f32_32x32x16_f16(pfr[kk], kt0[kk], o0, 0,0,0);\
      o1 = __builtin_amdgcn_mfma_f32_32x32x16_f16(pfr[kk], kt1[kk], o1, 0,0,0);\
    }                                                                         \
    __builtin_amdgcn_s_setprio(0);                                            \
  }

  for (int it = 0; it < 16; ++it) {
    ATT_TILE(0, 0)          // even jt
    ATT_TILE(2048, 1024)    // odd jt
    qP += 4096;
    ktP += 4096;
  }
#undef ATT_TILE

  // ---- flash merge of the two j-halves ----
  mM[i_sub][jh][l31]  = mreg;
  lsM[i_sub][jh][l31] = ls + __shfl_xor(ls, 32);
  __syncthreads();

  if (jh == 1) {
#pragma unroll
    for (int r = 0; r < 16; ++r) {
      const int il = (r & 3) + 8 * (r >> 2) + 4 * hi;
      const float mS = fmaxf(mM[i_sub][0][il], mM[i_sub][1][il]);
      const float f = fexp2(mM[i_sub][1][il] - mS);
      obuf[i_sub][r][lane]      = o0[r] * f;
      obuf[i_sub][r + 16][lane] = o1[r] * f;
    }
  }
  __syncthreads();
  if (jh == 0) {
#pragma unroll
    for (int r = 0; r < 16; ++r) {
      const int il = (r & 3) + 8 * (r >> 2) + 4 * hi;
      const float mA = mM[i_sub][0][il], mB = mM[i_sub][1][il];
      const float mS = fmaxf(mA, mB);
      const float fA = fexp2(mA - mS);
      const float fB = fexp2(mB - mS);
      const float lsS = lsM[i_sub][0][il] * fA + lsM[i_sub][1][il] * fB;
      const float inv = 1.0f / lsS;
      const size_t rowb = ((size_t)bh * NTOK + i0 + il) * HD;
      out[rowb + l31]      = (o0[r] * fA + obuf[i_sub][r][lane]) * inv;
      out[rowb + 32 + l31] = (o1[r] * fA + obuf[i_sub][r + 16][lane]) * inv;
    }
  }
}

extern "C" void kernel_launch(void* const* d_in, const int* in_sizes, int n_in,
                              void* d_out, int out_size, void* d_ws, size_t ws_size,
                              hipStream_t stream) {
  const float* x  = (const float*)d_in[0];
  const float* Wk = (const float*)d_in[1];
  const float* Wq = (const float*)d_in[2];
  // d_in[3] (Wv) is dead code in the reference — never read.
  float* out = (float*)d_out;

  // ws (f16 elems): [xb|KTp: 8388608][Wkb: 1048576][Wqb: 1048576]
  //                 [Kp: 8388608][Qp: 8388608]
  _Float16* xb  = (_Float16*)d_ws;
  _Float16* KTp = xb;
  _Float16* Wkb = xb + (size_t)8388608;
  _Float16* Wqb = Wkb + (size_t)1048576;
  _Float16* Kp  = Wqb + (size_t)1048576;
  _Float16* Qp  = Kp + (size_t)8388608;

  cvt_f32_f16<<<8192, 256, 0, stream>>>(x, xb, 2097152, 1.0f);
  cvt_w<<<dim3(1024, 2), 256, 0, stream>>>(Wk, Wq, Wkb, Wqb);

  dim3 ggrid(MROWS / 128, DMODEL / 128, 2);   // z=0 -> Kp, z=1 -> Qp
  gemm_pack_f16<<<ggrid, 256, 0, stream>>>(xb, Wkb, Wqb, Kp, Qp);

  pack_kt<<<2048, 256, 0, stream>>>(Kp, KTp);

  attn_mfma<<<2048, 256, 0, stream>>>(Kp, Qp, KTp, out);
}

// Round 17
// 170.041 us; speedup vs baseline: 4.3901x; 1.0441x over previous
//
#include <hip/hip_runtime.h>
#include <cstdint>
#include <cstddef>

#define NTOK 2048
#define DMODEL 1024
#define HD 64
#define MROWS 8192

using f16x8  = __attribute__((ext_vector_type(8))) _Float16;
using f16x4  = __attribute__((ext_vector_type(4))) _Float16;
using f32x4  = __attribute__((ext_vector_type(4))) float;
using f32x16 = __attribute__((ext_vector_type(16))) float;
using u32x4  = __attribute__((ext_vector_type(4))) unsigned int;

#define Z16 {0.f,0.f,0.f,0.f,0.f,0.f,0.f,0.f,0.f,0.f,0.f,0.f,0.f,0.f,0.f,0.f}

__device__ __forceinline__ unsigned pkf16(float a, float b) {
  return __builtin_bit_cast(unsigned, __builtin_amdgcn_cvt_pkrtz(a, b));
}
__device__ __forceinline__ void plswap(unsigned &a, unsigned &b) {
  auto r = __builtin_amdgcn_permlane32_swap(a, b, false, false);
  a = r[0]; b = r[1];
}
__device__ __forceinline__ float fexp2(float x) {
  return __builtin_amdgcn_exp2f(x);
}
__device__ __forceinline__ float fmax3(float a, float b, float c) {
  return fmaxf(fmaxf(a, b), c);
}

// ---------------------------------------------------------------------------
// f32 -> f16 convert (x)
// ---------------------------------------------------------------------------
__global__ __launch_bounds__(256) void cvt_f32_f16(const float* __restrict__ in,
                                                   _Float16* __restrict__ out,
                                                   int n4, float scale) {
  int idx = blockIdx.x * 256 + threadIdx.x;
  if (idx < n4) {
    float4 v = reinterpret_cast<const float4*>(in)[idx];
    f16x4 o;
    o.x = (_Float16)(v.x * scale); o.y = (_Float16)(v.y * scale);
    o.z = (_Float16)(v.z * scale); o.w = (_Float16)(v.w * scale);
    reinterpret_cast<f16x4*>(out)[idx] = o;
  }
}

// both weight matrices in one launch; log2(e) folded into Wq
__global__ __launch_bounds__(256) void cvt_w(const float* __restrict__ Wk,
                                             const float* __restrict__ Wq,
                                             _Float16* __restrict__ Wkb,
                                             _Float16* __restrict__ Wqb) {
  const int idx = blockIdx.x * 256 + threadIdx.x;
  const float* in = blockIdx.y ? Wq : Wk;
  _Float16* out = blockIdx.y ? Wqb : Wkb;
  const float scale = blockIdx.y ? 1.4426950408889634f : 1.0f;
  float4 v = reinterpret_cast<const float4*>(in)[idx];
  f16x4 o;
  o.x = (_Float16)(v.x * scale); o.y = (_Float16)(v.y * scale);
  o.z = (_Float16)(v.z * scale); o.w = (_Float16)(v.w * scale);
  reinterpret_cast<f16x4*>(out)[idx] = o;
}

// ---------------------------------------------------------------------------
// f16 MFMA GEMM with FUSED PACK epilogue. z=0 -> Kp (and, when emitKT,
// also KTp directly from the LDS tile — deletes the pack_kt kernel and its
// 67 MB L2 round-trip); z=1 -> Qp.
//   Qp/Kp[bh][rt(32rows)][ks][lane][8] = Y_head[rt*32+(l&31)][ks*16+(l>>5)*8+e]
//   KTp[bh][jt(64rows)][ds][ks][lane][8]
//     = K_head[jt*64+ks*16+(l>>5)*8+e][ds*32+(l&31)]
// KT gather from T: lanes 0-31 read consecutive 2B (16 banks x dword-merged
// pairs), half-wave rows +8 -> same banks = 2-way aliasing = free (m136).
// ---------------------------------------------------------------------------
#define GLDS16(g, l) __builtin_amdgcn_global_load_lds(                      \
    (const __attribute__((address_space(1))) void*)(g),                     \
    (__attribute__((address_space(3))) void*)(l), 16, 0, 0)

__global__ __launch_bounds__(256) void gemm_pack_f16(
    const _Float16* __restrict__ X,
    const _Float16* __restrict__ Wk,
    const _Float16* __restrict__ Wq,
    _Float16* __restrict__ Kp,
    _Float16* __restrict__ Qp,
    _Float16* __restrict__ KTp,
    int emitKT) {
  const bool isQ = blockIdx.z != 0;
  const _Float16* __restrict__ W = isQ ? Wq : Wk;

  __shared__ _Float16 arena[17408];
  _Float16* As = arena;           // [2][4096]
  _Float16* Bs = arena + 8192;    // [2][4096]

  const int tid = threadIdx.x;
  const int lane = tid & 63;
  const int w = tid >> 6;
  const int m0 = blockIdx.x * 128;
  const int o0 = blockIdx.y * 128;

  const int srow = w * 32 + (lane >> 2);
  const int scol = (lane & 3) * 8;
  const _Float16* xsrc = X + (size_t)(m0 + srow) * DMODEL + scol;
  const _Float16* wsrc = W + (size_t)(o0 + srow) * DMODEL + scol;

  const int wr = w >> 1, wc = w & 1;
  const int arow = lane & 15, kg = lane >> 4;
  const int l31 = lane & 31, hi8 = (lane >> 5) * 8;

  f32x4 zero = {0.f, 0.f, 0.f, 0.f};
  f32x4 acc[4][4];
#pragma unroll
  for (int mi = 0; mi < 4; ++mi)
#pragma unroll
    for (int ni = 0; ni < 4; ++ni) acc[mi][ni] = zero;

  GLDS16(xsrc,               &As[(w * 32) * 32]);
  GLDS16(xsrc + 16 * DMODEL, &As[(w * 32 + 16) * 32]);
  GLDS16(wsrc,               &Bs[(w * 32) * 32]);
  GLDS16(wsrc + 16 * DMODEL, &Bs[(w * 32 + 16) * 32]);

  for (int kt = 0; kt < 32; ++kt) {
    __syncthreads();
    if (kt + 1 < 32) {
      const int ko = (kt + 1) * 32;
      const int bo = ((kt + 1) & 1) * 4096;
      GLDS16(xsrc + ko,               &As[bo + (w * 32) * 32]);
      GLDS16(xsrc + ko + 16 * DMODEL, &As[bo + (w * 32 + 16) * 32]);
      GLDS16(wsrc + ko,               &Bs[bo + (w * 32) * 32]);
      GLDS16(wsrc + ko + 16 * DMODEL, &Bs[bo + (w * 32 + 16) * 32]);
    }
    const int bo = (kt & 1) * 4096;
    f16x8 af[4], bfr[4];
#pragma unroll
    for (int mi = 0; mi < 4; ++mi)
      af[mi] = *reinterpret_cast<const f16x8*>(
          &As[bo + (wr * 64 + mi * 16 + arow) * 32 + kg * 8]);
#pragma unroll
    for (int ni = 0; ni < 4; ++ni)
      bfr[ni] = *reinterpret_cast<const f16x8*>(
          &Bs[bo + (wc * 64 + ni * 16 + arow) * 32 + kg * 8]);
#pragma unroll
    for (int mi = 0; mi < 4; ++mi)
#pragma unroll
      for (int ni = 0; ni < 4; ++ni)
        acc[mi][ni] = __builtin_amdgcn_mfma_f32_16x16x32_f16(
            af[mi], bfr[ni], acc[mi][ni], 0, 0, 0);
  }

  __syncthreads();
  _Float16* T = arena;             // [128][136]
#pragma unroll
  for (int mi = 0; mi < 4; ++mi)
#pragma unroll
    for (int ni = 0; ni < 4; ++ni)
#pragma unroll
      for (int r = 0; r < 4; ++r)
        T[(wr * 64 + mi * 16 + kg * 4 + r) * 136 + wc * 64 + ni * 16 + arow] =
            (_Float16)acc[mi][ni][r];
  __syncthreads();

  const int b = m0 >> 11;
  _Float16* RowDst = isQ ? Qp : Kp;
#pragma unroll
  for (int k = 0; k < 8; ++k) {
    const int c = w * 8 + k;
    const int hl = c >> 4, rtl = (c >> 2) & 3, ks = c & 3;
    f16x8 v = *reinterpret_cast<const f16x8*>(
        &T[(rtl * 32 + l31) * 136 + hl * 64 + ks * 16 + hi8]);
    const int bh = b * 16 + (o0 >> 6) + hl;
    const int rt = ((m0 & 2047) >> 5) + rtl;
    const size_t ch = ((size_t)(bh * 64 + rt) * 4 + ks) * 512 + (size_t)lane * 8;
    *reinterpret_cast<f16x8*>(&RowDst[ch]) = v;
  }

  // ---- fused KT emission (K branch only): 32 chunks per block ----
  if (!isQ && emitKT) {
#pragma unroll
    for (int k = 0; k < 8; ++k) {
      const int c = w * 8 + k;                 // (hl, jtl, ds, ks)
      const int hl = c >> 4, jtl = (c >> 3) & 1, ds = (c >> 2) & 1, ks = c & 3;
      const int row0 = jtl * 64 + ks * 16 + (lane >> 5) * 8;
      const int col = hl * 64 + ds * 32 + l31;
      f16x8 v;
#pragma unroll
      for (int e = 0; e < 8; ++e) v[e] = T[(row0 + e) * 136 + col];
      const int bh = b * 16 + (o0 >> 6) + hl;
      const int jt = ((m0 & 2047) >> 6) + jtl;
      const size_t ch =
          (((size_t)(bh * 32 + jt) * 2 + ds) * 4 + ks) * 512 + (size_t)lane * 8;
      *reinterpret_cast<f16x8*>(&KTp[ch]) = v;
    }
  }
}

// ---------------------------------------------------------------------------
// pack_kt (fallback when ws too small to give KTp its own region)
// ---------------------------------------------------------------------------
__global__ __launch_bounds__(256) void pack_kt(
    const _Float16* __restrict__ Kp,
    _Float16* __restrict__ KTp) {
  const int blk = blockIdx.x;
  const int bh = blk >> 5;
  const int t64 = blk & 31;
  const int tid = threadIdx.x;
  const int l = tid & 63;

  __shared__ _Float16 t[64][72];
#pragma unroll
  for (int pass = 0; pass < 2; ++pass) {
    const int idx = pass * 4 + (tid >> 6);
    const int rs = idx >> 2, ks = idx & 3;
    f16x8 v = *reinterpret_cast<const f16x8*>(
        &Kp[((size_t)(bh * 64 + t64 * 2 + rs) * 4 + ks) * 512 + (size_t)l * 8]);
    *reinterpret_cast<f16x8*>(&t[rs * 32 + (l & 31)][ks * 16 + (l >> 5) * 8]) = v;
  }
  __syncthreads();
#pragma unroll
  for (int pass = 0; pass < 2; ++pass) {
    const int idx = pass * 4 + (tid >> 6);
    const int ds = idx >> 2, ks = idx & 3;
    const int row0 = ks * 16 + (l >> 5) * 8;
    const int col = ds * 32 + (l & 31);
    f16x8 v;
#pragma unroll
    for (int e = 0; e < 8; ++e) v[e] = t[row0 + e][col];
    const size_t ch = (((size_t)(bh * 32 + t64) * 2 + ds) * 4 + ks) * 512 + (size_t)l * 8;
    *reinterpret_cast<f16x8*>(&KTp[ch]) = v;
  }
}

// ---------------------------------------------------------------------------
// Swapped-operand MFMA flash attention, SPLIT-J (flash merge) — exact r15
// inner loop (best measured: 110.0-110.7 us). r16's f16-exp/fdot2/pointer
// diet was a null->regression (more insts: 16 cvt + 16 exp + 16 pack ops vs
// 16 exp + 8 cvt_pkrtz), reverted.
// ---------------------------------------------------------------------------
__global__ __launch_bounds__(256, 3) void attn_mfma(
    const _Float16* __restrict__ Kp,
    const _Float16* __restrict__ Qp,
    const _Float16* __restrict__ KTp,
    float* __restrict__ out) {
  const int bid = blockIdx.x;
  const int myid = (bid & 7) * 256 + (bid >> 3);   // 2048 blocks, bijective
  const int bh = myid >> 5;                        // 32 blocks per head
  const int itile = myid & 31;
  const int tid = threadIdx.x, lane = tid & 63, w = tid >> 6;
  const int l31 = lane & 31;
  const int hi = lane >> 5;
  const int i_sub = w & 1;
  const int jh = w >> 1;
  const int i0 = itile * 64 + i_sub * 32;

  const _Float16* kpp  = Kp  + (size_t)bh * 131072 + lane * 8;
  const _Float16* qpp  = Qp  + (size_t)bh * 131072 + lane * 8;
  const _Float16* ktpp = KTp + (size_t)bh * 131072 + lane * 8;

  __shared__ float scl[4][32];
  __shared__ float mM[2][2][32];
  __shared__ float lsM[2][2][32];
  __shared__ float obuf[2][32][64];

  f16x8 kbf[4];
#pragma unroll
  for (int ks = 0; ks < 4; ++ks)
    kbf[ks] = *reinterpret_cast<const f16x8*>(
        kpp + ((size_t)(i0 >> 5) * 4 + ks) * 512);

  const f32x16 z16v = Z16;
  f32x16 o0 = z16v, o1 = z16v;
  float mreg = -1e30f, ls = 0.f;

  const int jt0 = jh * 32;
  for (int jt = jt0; jt < jt0 + 32; ++jt) {
    f16x8 q[4];
#pragma unroll
    for (int ks = 0; ks < 4; ++ks)
      q[ks] = *reinterpret_cast<const f16x8*>(qpp + ((size_t)jt * 4 + ks) * 512);

    f32x16 s = z16v;
    __builtin_amdgcn_s_setprio(1);
#pragma unroll
    for (int ks = 0; ks < 4; ++ks)
      s = __builtin_amdgcn_mfma_f32_32x32x16_f16(q[ks], kbf[ks], s, 0, 0, 0);
    __builtin_amdgcn_s_setprio(0);

    f16x8 kt0[2], kt1[2];
    {
      const size_t base = ((size_t)(jt >> 1) * 8 + (size_t)(jt & 1) * 2) * 512;
#pragma unroll
      for (int kk = 0; kk < 2; ++kk) {
        kt0[kk] = *reinterpret_cast<const f16x8*>(ktpp + base + (size_t)kk * 512);
        kt1[kk] = *reinterpret_cast<const f16x8*>(ktpp + base + (size_t)(4 + kk) * 512);
      }
    }

    // row max via v_max3
    float t0 = fmax3(s[0], s[1], s[2]);
    float t1 = fmax3(s[3], s[4], s[5]);
    float t2 = fmax3(s[6], s[7], s[8]);
    float t3 = fmax3(s[9], s[10], s[11]);
    float t4 = fmax3(s[12], s[13], s[14]);
    float pm = fmaxf(fmax3(t0, t1, t2), fmax3(t3, t4, s[15]));
    pm = fmaxf(pm, __shfl_xor(pm, 32));

    if (!__all(pm <= mreg + 8.0f)) {
      const float mn = fmaxf(mreg, pm);
      const float sc = fexp2(mreg - mn);
      ls *= sc;
      mreg = mn;
      scl[w][l31] = sc;
#pragma unroll
      for (int r = 0; r < 16; ++r) {
        const int il = (r & 3) + 8 * (r >> 2) + 4 * hi;
        const float scr = scl[w][il];
        o0[r] *= scr; o1[r] *= scr;
      }
    }

#pragma unroll
    for (int r = 0; r < 16; ++r) s[r] = fexp2(s[r] - mreg);
    {
      float l0 = (s[0] + s[4]) + (s[8] + s[12]);
      float l1 = (s[1] + s[5]) + (s[9] + s[13]);
      float l2 = (s[2] + s[6]) + (s[10] + s[14]);
      float l3 = (s[3] + s[7]) + (s[11] + s[15]);
      ls += (l0 + l1) + (l2 + l3);
    }

    f16x8 pfr[2];
    {
      unsigned a0 = pkf16(s[0], s[1]),  b0 = pkf16(s[4], s[5]);
      unsigned a1 = pkf16(s[2], s[3]),  b1 = pkf16(s[6], s[7]);
      plswap(a0, b0); plswap(a1, b1);
      u32x4 t; t[0] = a0; t[1] = a1; t[2] = b0; t[3] = b1;
      pfr[0] = __builtin_bit_cast(f16x8, t);
      unsigned a2 = pkf16(s[8], s[9]),   b2 = pkf16(s[12], s[13]);
      unsigned a3 = pkf16(s[10], s[11]), b3 = pkf16(s[14], s[15]);
      plswap(a2, b2); plswap(a3, b3);
      t[0] = a2; t[1] = a3; t[2] = b2; t[3] = b3;
      pfr[1] = __builtin_bit_cast(f16x8, t);
    }

    __builtin_amdgcn_s_setprio(1);
#pragma unroll
    for (int kk = 0; kk < 2; ++kk) {
      o0 = __builtin_amdgcn_mfma_f32_32x32x16_f16(pfr[kk], kt0[kk], o0, 0, 0, 0);
      o1 = __builtin_amdgcn_mfma_f32_32x32x16_f16(pfr[kk], kt1[kk], o1, 0, 0, 0);
    }
    __builtin_amdgcn_s_setprio(0);
  }

  // ---- flash merge of the two j-halves ----
  mM[i_sub][jh][l31]  = mreg;
  lsM[i_sub][jh][l31] = ls + __shfl_xor(ls, 32);
  __syncthreads();

  if (jh == 1) {
#pragma unroll
    for (int r = 0; r < 16; ++r) {
      const int il = (r & 3) + 8 * (r >> 2) + 4 * hi;
      const float mS = fmaxf(mM[i_sub][0][il], mM[i_sub][1][il]);
      const float f = fexp2(mM[i_sub][1][il] - mS);
      obuf[i_sub][r][lane]      = o0[r] * f;
      obuf[i_sub][r + 16][lane] = o1[r] * f;
    }
  }
  __syncthreads();
  if (jh == 0) {
#pragma unroll
    for (int r = 0; r < 16; ++r) {
      const int il = (r & 3) + 8 * (r >> 2) + 4 * hi;
      const float mA = mM[i_sub][0][il], mB = mM[i_sub][1][il];
      const float mS = fmaxf(mA, mB);
      const float fA = fexp2(mA - mS);
      const float fB = fexp2(mB - mS);
      const float lsS = lsM[i_sub][0][il] * fA + lsM[i_sub][1][il] * fB;
      const float inv = 1.0f / lsS;
      const size_t rowb = ((size_t)bh * NTOK + i0 + il) * HD;
      out[rowb + l31]      = (o0[r] * fA + obuf[i_sub][r][lane]) * inv;
      out[rowb + 32 + l31] = (o1[r] * fA + obuf[i_sub][r + 16][lane]) * inv;
    }
  }
}

extern "C" void kernel_launch(void* const* d_in, const int* in_sizes, int n_in,
                              void* d_out, int out_size, void* d_ws, size_t ws_size,
                              hipStream_t stream) {
  const float* x  = (const float*)d_in[0];
  const float* Wk = (const float*)d_in[1];
  const float* Wq = (const float*)d_in[2];
  // d_in[3] (Wv) is dead code in the reference — never read.
  float* out = (float*)d_out;

  // Preferred ws layout (f16 elems, 71.3 MB):
  //   xb[8388608] Wkb[1048576] Wqb[1048576] Kp[8388608] Qp[8388608] KTp[8388608]
  // (KTp cannot alias xb when fused: gemm reads X while writing KTp.)
  // Fallback (54.5 MB, r15 schedule): KTp aliases xb, separate pack_kt pass.
  _Float16* xb  = (_Float16*)d_ws;
  _Float16* Wkb = xb + (size_t)8388608;
  _Float16* Wqb = Wkb + (size_t)1048576;
  _Float16* Kp  = Wqb + (size_t)1048576;
  _Float16* Qp  = Kp + (size_t)8388608;
  const bool fuseKT = ws_size >= (size_t)71303168;
  _Float16* KTp = fuseKT ? (Qp + (size_t)8388608) : xb;

  cvt_f32_f16<<<8192, 256, 0, stream>>>(x, xb, 2097152, 1.0f);
  cvt_w<<<dim3(1024, 2), 256, 0, stream>>>(Wk, Wq, Wkb, Wqb);

  dim3 ggrid(MROWS / 128, DMODEL / 128, 2);   // z=0 -> Kp(+KTp), z=1 -> Qp
  gemm_pack_f16<<<ggrid, 256, 0, stream>>>(xb, Wkb, Wqb, Kp, Qp, KTp,
                                           fuseKT ? 1 : 0);

  if (!fuseKT) pack_kt<<<2048, 256, 0, stream>>>(Kp, KTp);

  attn_mfma<<<2048, 256, 0, stream>>>(Kp, Qp, KTp, out);
}